// Round 1
// baseline (455.682 us; speedup 1.0000x reference)
//
#include <hip/hip_runtime.h>
#include <stdint.h>
#include <math.h>

#define M_DIM 8192
#define N_DIM 4096
#define K_DIM 4096
#define BITWIDTH 7

// GEMM geometry: 256x256 block tile, 512 threads = 8 waves (2M x 4N),
// wave tile 128x64 as 4x2 of mfma_i32_32x32x32_i8.
// K staged in 64-byte K-tiles through a 4-slot LDS ring (128 KiB dynamic),
// counted-vmcnt prefetch distance 3 (vmcnt(8) steady state, never 0 in loop).
#define BM 256
#define BN 256
#define KT 64                    // bytes of K per tile
#define NT (K_DIM / KT)          // 64 K-tiles
#define TILEB (BM * KT)          // 16 KiB per operand per ring slot

using i32x4  = __attribute__((ext_vector_type(4)))  int;
using i32x16 = __attribute__((ext_vector_type(16))) int;

// ---------------------------------------------------------------------------
// Fused pack: int32 (int8-range values) -> int8 for BOTH tensors, one launch.
// 8 elements (32B read, 8B write) per thread, block-aligned split.
// Also zero-inits the maxabs scalar (replaces a memset dispatch).
// ---------------------------------------------------------------------------
__global__ __launch_bounds__(256) void pack_both_kernel(
        const int* __restrict__ act, const int* __restrict__ wt,
        uint32_t* __restrict__ act8, uint32_t* __restrict__ w8,
        int* __restrict__ maxabs) {
    if (blockIdx.x == 0 && threadIdx.x == 0) *maxabs = 0;
    const int ACT_N8 = (M_DIM * K_DIM) / 8;   // 4194304
    int i = blockIdx.x * blockDim.x + threadIdx.x;
    const int* src;
    uint32_t* dst;
    if (i < ACT_N8) { src = act; dst = act8; }
    else            { src = wt;  dst = w8;  i -= ACT_N8; }
    int4 a = ((const int4*)src)[2 * i];
    int4 b = ((const int4*)src)[2 * i + 1];
    uint32_t p0 = (uint32_t)(a.x & 0xFF) | ((uint32_t)(a.y & 0xFF) << 8)
                | ((uint32_t)(a.z & 0xFF) << 16) | ((uint32_t)(a.w & 0xFF) << 24);
    uint32_t p1 = (uint32_t)(b.x & 0xFF) | ((uint32_t)(b.y & 0xFF) << 8)
                | ((uint32_t)(b.z & 0xFF) << 16) | ((uint32_t)(b.w & 0xFF) << 24);
    ((uint2*)dst)[i] = make_uint2(p0, p1);
}

// ---------------------------------------------------------------------------
// async global->LDS, 16B per lane, LDS dest = wave-uniform base + lane*16
// ---------------------------------------------------------------------------
__device__ __forceinline__ void gload_lds16(const int8_t* g, int8_t* lds) {
    __builtin_amdgcn_global_load_lds(
        (__attribute__((address_space(1))) void*)g,
        (__attribute__((address_space(3))) void*)lds,
        16, 0, 0);
}

// ---------------------------------------------------------------------------
// i8 GEMM, 8-phase-style pipelined schedule (T2+T3+T4+T5):
//   - 4-slot LDS ring; while computing K-tile t (slot t&3), stage t+3 into
//     slot (t+3)&3 (== (t-1)&3, whose readers finished before tile t-1's
//     final barrier: lgkmcnt(0) precedes it in every wave's program order).
//   - per K-tile 2 phases (one per 32B k-step): 6 ds_read_b128 + 2 gloads,
//     raw s_barrier, lgkmcnt(0), setprio(1) 8xMFMA setprio(0), s_barrier.
//   - one counted vmcnt per K-tile: steady vmcnt(8) leaves tiles t+2,t+3
//     (8 loads) in flight, guarantees t+1 landed. Each wave waits its OWN
//     vmcnt before the shared barrier -> cross-wave LDS visibility.
//   - LDS swizzle: 64B rows, 4x16B chunks; slot c holds global chunk
//     c ^ ((row>>1)&3) via pre-swizzled global source (gload dest linear);
//     fragment reads apply the same XOR -> balanced bank groups.
// ---------------------------------------------------------------------------
__global__ __launch_bounds__(512, 2) void gemm_i8(
        const int8_t* __restrict__ A8, const int8_t* __restrict__ B8,
        int* __restrict__ C, int* __restrict__ maxabs) {
    extern __shared__ int8_t smem[];
    int8_t* As = smem;                 // 4 * 16 KiB ring, A operand
    int8_t* Bs = smem + 4 * TILEB;     // 4 * 16 KiB ring, B operand

    const int tid  = threadIdx.x;
    const int wave = tid >> 6;
    const int lane = tid & 63;
    const int fr   = lane & 31;
    const int hl   = lane >> 5;

    // Bijective XCD column-panel swizzle: 512 blocks, each XCD owns 2
    // B-column panels (512 cols x 4096 K = 2 MB, L2-resident per XCD).
    const int orig = blockIdx.x;
    const int xcd  = orig & 7;
    const int idx  = orig >> 3;            // 0..63 within XCD
    const int bx   = xcd * 2 + (idx >> 5); // 0..15
    const int by   = idx & 31;             // 0..31

    const int row0 = by * BM;
    const int col0 = bx * BN;
    const int wm   = (wave >> 2) * 128;    // wave row offset in block tile
    const int wn   = (wave & 3) * 64;      // wave col offset

    i32x16 acc[4][2];
#pragma unroll
    for (int i = 0; i < 4; ++i)
#pragma unroll
        for (int j = 0; j < 2; ++j)
            acc[i][j] = (i32x16)(0);

    // --- staging addressing -------------------------------------------------
    // Element e = g*512 + wave*64 + lane covers row e>>2, LDS slot chunk e&3.
    // Source chunk pre-swizzled: (lane&3) ^ ((lane>>3)&3) == slot ^ ((row>>1)&3).
    const int srow = wave * 16 + (lane >> 2);
    const int schk = ((lane & 3) ^ ((lane >> 3) & 3)) << 4;
    const int8_t* aS = A8 + (size_t)(row0 + srow) * K_DIM + schk;
    const int8_t* bS = B8 + (size_t)(col0 + srow) * K_DIM + schk;
    const int ldso = wave * 1024;          // wave-uniform LDS dest offset

    // --- fragment addressing (loop-invariant) -------------------------------
    // 32x32x32 i8: row = lane&31, k-bytes = kk*32 + hl*16 -> logical chunk
    // 2*kk + hl; LDS slot = chunk ^ ((row>>1)&3) = chunk ^ ((fr>>1)&3).
    int aoff[2][4], boff[2][2];
#pragma unroll
    for (int kk = 0; kk < 2; ++kk) {
        const int slot = ((2 * kk + hl) ^ ((fr >> 1) & 3)) << 4;
#pragma unroll
        for (int i = 0; i < 4; ++i)
            aoff[kk][i] = (wm + i * 32 + fr) * KT + slot;
#pragma unroll
        for (int j = 0; j < 2; ++j)
            boff[kk][j] = (wn + j * 32 + fr) * KT + slot;
    }

    // --- prologue: stage K-tiles 0,1,2 into ring slots 0,1,2 ---------------
#pragma unroll
    for (int pt = 0; pt < 3; ++pt) {
        const int sb = pt * TILEB;
        const size_t ko = (size_t)pt * KT;
        gload_lds16(aS + ko,                          As + sb + ldso);
        gload_lds16(aS + ko + (size_t)128 * K_DIM,    As + sb + 8192 + ldso);
        gload_lds16(bS + ko,                          Bs + sb + ldso);
        gload_lds16(bS + ko + (size_t)128 * K_DIM,    Bs + sb + 8192 + ldso);
    }
    asm volatile("s_waitcnt vmcnt(8)" ::: "memory");  // tile 0 landed
    __builtin_amdgcn_s_barrier();

    // --- main K loop --------------------------------------------------------
    for (int t = 0; t < NT; ++t) {
        const int rb = (t & 3) * TILEB;
        const int sb = ((t + 3) & 3) * TILEB;
        const size_t ko = (size_t)(t + 3) * KT;
        const bool st = (t < NT - 3);

        i32x4 af[4], bf[2];

        // ---- phase 0: k-step 0; stage A of tile t+3 ----
#pragma unroll
        for (int i = 0; i < 4; ++i) af[i] = *(const i32x4*)(As + rb + aoff[0][i]);
#pragma unroll
        for (int j = 0; j < 2; ++j) bf[j] = *(const i32x4*)(Bs + rb + boff[0][j]);
        if (st) {
            gload_lds16(aS + ko,                       As + sb + ldso);
            gload_lds16(aS + ko + (size_t)128 * K_DIM, As + sb + 8192 + ldso);
        }
        __builtin_amdgcn_s_barrier();
        asm volatile("s_waitcnt lgkmcnt(0)" ::: "memory");
        __builtin_amdgcn_s_setprio(1);
#pragma unroll
        for (int i = 0; i < 4; ++i)
#pragma unroll
            for (int j = 0; j < 2; ++j)
                acc[i][j] = __builtin_amdgcn_mfma_i32_32x32x32_i8(
                    af[i], bf[j], acc[i][j], 0, 0, 0);
        __builtin_amdgcn_s_setprio(0);
        __builtin_amdgcn_s_barrier();

        // ---- phase 1: k-step 1; stage B of tile t+3; counted vmcnt ----
#pragma unroll
        for (int i = 0; i < 4; ++i) af[i] = *(const i32x4*)(As + rb + aoff[1][i]);
#pragma unroll
        for (int j = 0; j < 2; ++j) bf[j] = *(const i32x4*)(Bs + rb + boff[1][j]);
        if (st) {
            gload_lds16(bS + ko,                       Bs + sb + ldso);
            gload_lds16(bS + ko + (size_t)128 * K_DIM, Bs + sb + 8192 + ldso);
        }
        // wait: next tile's 4 loads done; newer tiles stay in flight
        if (t < NT - 3)       asm volatile("s_waitcnt vmcnt(8)" ::: "memory");
        else if (t == NT - 3) asm volatile("s_waitcnt vmcnt(4)" ::: "memory");
        else if (t == NT - 2) asm volatile("s_waitcnt vmcnt(0)" ::: "memory");
        __builtin_amdgcn_s_barrier();
        asm volatile("s_waitcnt lgkmcnt(0)" ::: "memory");
        __builtin_amdgcn_s_setprio(1);
#pragma unroll
        for (int i = 0; i < 4; ++i)
#pragma unroll
            for (int j = 0; j < 2; ++j)
                acc[i][j] = __builtin_amdgcn_mfma_i32_32x32x32_i8(
                    af[i], bf[j], acc[i][j], 0, 0, 0);
        __builtin_amdgcn_s_setprio(0);
        __builtin_amdgcn_s_barrier();
    }

    // epilogue: 32x32 C/D layout: col = lane&31,
    // row = (reg&3) + 8*(reg>>2) + 4*(lane>>5)   [m74/m101, dtype-independent]
    int mymax = 0;
    const int ccol  = fr;
    const int rbase = hl << 2;
#pragma unroll
    for (int i = 0; i < 4; ++i) {
#pragma unroll
        for (int j = 0; j < 2; ++j) {
            int* p = C + (size_t)(row0 + wm + i * 32) * N_DIM
                       + (col0 + wn + j * 32 + ccol);
#pragma unroll
            for (int r = 0; r < 16; ++r) {
                int row = (r & 3) + 8 * (r >> 2) + rbase;
                int v = acc[i][j][r];
                p[(size_t)row * N_DIM] = v;
                int a = v < 0 ? -v : v;
                mymax = a > mymax ? a : mymax;
            }
        }
    }

    // wave-reduce max, then one atomic per block (wmaxs reuses LDS; all
    // K-loop LDS reads completed before the loop's final barrier)
#pragma unroll
    for (int off = 32; off > 0; off >>= 1) {
        int o = __shfl_down(mymax, off, 64);
        mymax = o > mymax ? o : mymax;
    }
    if (lane == 0) ((volatile int*)smem)[wave] = mymax;
    __syncthreads();
    if (tid == 0) {
        int bmx = ((volatile int*)smem)[0];
        for (int w = 1; w < 8; ++w) {
            int x = ((volatile int*)smem)[w];
            bmx = x > bmx ? x : bmx;
        }
        atomicMax(maxabs, bmx);
    }
}

// ---------------------------------------------------------------------------
// Pseudo-stochastic shift, faithful to PstoShiftInt32 (all-integer, exact).
// Returns the int8 result sign-extended to int32.
// ---------------------------------------------------------------------------
__device__ __forceinline__ int psto(int x, int eff) {
    if (eff > 0) {
        int rt   = x >> eff;                 // floor divide by 2^eff
        int prob = x & ((1 << eff) - 1);     // non-negative floor remainder
        int h    = eff >> 1;
        int qp   = prob >> h;
        int prn  = (prob & ((1 << h) - 1)) << (eff & 1);
        int sgn  = (x > 0) - (x < 0);
        int r    = rt + ((qp <= prn) ? 0 : sgn);
        r = r < -127 ? -127 : r;
        r = r > 127 ? 127 : r;
        return r;
    }
    return (int)(int8_t)x;                   // wrapping int8 cast, as in torch
}

// ---------------------------------------------------------------------------
// In-place: read int32 acc from C, write int32 quantized value back.
// 8 elements (two int4) per thread. d_out is an int32 buffer.
// ---------------------------------------------------------------------------
__global__ __launch_bounds__(256) void finalize_kernel(int* __restrict__ C,
        const int* __restrict__ maxabs,
        const int* __restrict__ exp_in,
        const int* __restrict__ wexp) {
    const int m = *maxabs;
    int bw = 0;
    if (m != 0) bw = (int)ceilf(log2f((float)m));   // float32 path, as reference
    const int shift = bw - BITWIDTH;
    const int eff = (shift > 1) ? shift : ((shift == 1) ? 2 : 0);

    const size_t idx = ((size_t)blockIdx.x * blockDim.x + threadIdx.x) * 8;
    int4 v0 = *(const int4*)(C + idx);
    int4 v1 = *(const int4*)(C + idx + 4);
    int4 o0, o1;
    o0.x = psto(v0.x, eff); o0.y = psto(v0.y, eff);
    o0.z = psto(v0.z, eff); o0.w = psto(v0.w, eff);
    o1.x = psto(v1.x, eff); o1.y = psto(v1.y, eff);
    o1.z = psto(v1.z, eff); o1.w = psto(v1.w, eff);
    *(int4*)(C + idx) = o0;
    *(int4*)(C + idx + 4) = o1;

    if (idx == 0) {
        C[(size_t)M_DIM * N_DIM] = (int)(int8_t)(exp_in[0] + wexp[0] + eff);
    }
}

// ---------------------------------------------------------------------------
extern "C" void kernel_launch(void* const* d_in, const int* in_sizes, int n_in,
                              void* d_out, int out_size, void* d_ws, size_t ws_size,
                              hipStream_t stream) {
    const int* act    = (const int*)d_in[0];
    const int* exp_in = (const int*)d_in[1];
    const int* wt     = (const int*)d_in[2];
    const int* wexp   = (const int*)d_in[3];

    int8_t* act8   = (int8_t*)d_ws;                          // 32 MB
    int8_t* w8     = act8 + (size_t)M_DIM * K_DIM;           // 16 MB
    int*    maxabs = (int*)(w8 + (size_t)N_DIM * K_DIM);     // 4 B

    static int cfg_done = 0;
    if (!cfg_done) {
        hipFuncSetAttribute(reinterpret_cast<const void*>(gemm_i8),
                            hipFuncAttributeMaxDynamicSharedMemorySize,
                            8 * TILEB);                      // 128 KiB
        cfg_done = 1;
    }

    // 8 elem/thread over act (16384 blocks) then weight (8192 blocks).
    pack_both_kernel<<<24576, 256, 0, stream>>>(
        act, wt, (uint32_t*)act8, (uint32_t*)w8, maxabs);

    int* C = (int*)d_out;    // acc staged in-place in d_out
    gemm_i8<<<(M_DIM / BM) * (N_DIM / BN), 512, 8 * TILEB, stream>>>(
        act8, w8, C, maxabs);

    finalize_kernel<<<((size_t)M_DIM * N_DIM / 8) / 256, 256, 0, stream>>>(
        C, maxabs, exp_in, wexp);
}